// Round 1
// baseline (93.419 us; speedup 1.0000x reference)
//
#include <hip/hip_runtime.h>
#include <hip/hip_bf16.h>

// RotatedEmbedding: out[b,s,:] = (weight @ R)[ids[b,s], :]
// == gather-GEMM: Out[M=16384, N=1024] = W[ids[m], K=1024] * R[K,N]
// Strategy: convert R -> RT bf16 [N][K] (transposed for contiguous B frags),
// then fused gather + f32->bf16 convert + MFMA GEMM (16x16x32 bf16).

typedef __attribute__((ext_vector_type(4))) float f32x4;
typedef __attribute__((ext_vector_type(8))) short s16x8;

__device__ __forceinline__ short f2bf(float f) {
  unsigned u = __float_as_uint(f);
  unsigned r = (u + 0x7FFFu + ((u >> 16) & 1u)) >> 16;  // RNE
  return (short)r;
}

// R [K=1024][N=1024] f32  ->  RT [N=1024][K=1024] bf16(short)
__global__ __launch_bounds__(256) void convert_R_kernel(const float* __restrict__ R,
                                                        short* __restrict__ RT) {
  __shared__ float tile[32][33];
  const int bx = blockIdx.x;  // n-tile
  const int by = blockIdx.y;  // k-tile
  const int tx = threadIdx.x; // 0..31
  const int ty = threadIdx.y; // 0..7
#pragma unroll
  for (int i = 0; i < 4; ++i) {
    const int k = by * 32 + ty + i * 8;
    tile[ty + i * 8][tx] = R[(size_t)k * 1024 + bx * 32 + tx];
  }
  __syncthreads();
#pragma unroll
  for (int i = 0; i < 4; ++i) {
    const int n = bx * 32 + ty + i * 8;
    RT[(size_t)n * 1024 + by * 32 + tx] = f2bf(tile[tx][ty + i * 8]);
  }
}

#define LDT 72  // padded LDS leading dim (bf16 elems); 144B row stride, 16B-aligned

__global__ __launch_bounds__(256) void rot_embed_gemm(const float* __restrict__ W,
                                                      const short* __restrict__ RT,
                                                      const int* __restrict__ ids,
                                                      float* __restrict__ out) {
  __shared__ short sA[64][LDT];
  __shared__ short sB[64][LDT];
  __shared__ int sIds[64];

  const int t = threadIdx.x;

  // XCD-aware bijective swizzle: 4096 blocks, 8 XCDs -> contiguous 512-block
  // chunks per XCD so the 16 n-tiles sharing one m-tile's gathered rows hit
  // the same XCD L2.
  const int b = blockIdx.x;
  const int nwg = gridDim.x;  // 4096 (divisible by 8 -> bijective)
  const int swz = (b & 7) * (nwg >> 3) + (b >> 3);
  const int m0 = (swz >> 4) * 64;  // 256 m-tiles
  const int n0 = (swz & 15) * 64;  // 16 n-tiles

  if (t < 64) sIds[t] = ids[m0 + t];
  __syncthreads();

  const int lane = t & 63;
  const int w = t >> 6;      // wave 0..3
  const int wm = w & 1;      // wave m-offset (0/1 -> rows 0-31 / 32-63)
  const int wn = w >> 1;     // wave n-offset
  const int fr = lane & 15;  // fragment row (A) / col (B,D)
  const int fq = lane >> 4;  // 0..3

  // staging assignment: thread t loads row t/4, 16-elem segment t%4
  const int arow = t >> 2;
  const int aseg = (t & 3) << 4;
  const size_t wbase = (size_t)sIds[arow] * 1024 + aseg;
  const short* rtrow = RT + (size_t)(n0 + arow) * 1024 + aseg;

  f32x4 acc[2][2];
#pragma unroll
  for (int i = 0; i < 2; ++i)
#pragma unroll
    for (int j = 0; j < 2; ++j) acc[i][j] = (f32x4)0.0f;

  for (int k0 = 0; k0 < 1024; k0 += 64) {
    // ---- issue global loads (gathered A rows f32, B from RT bf16) ----
    const float* wp = W + wbase + k0;
    const f32x4 v0 = ((const f32x4*)wp)[0];
    const f32x4 v1 = ((const f32x4*)wp)[1];
    const f32x4 v2 = ((const f32x4*)wp)[2];
    const f32x4 v3 = ((const f32x4*)wp)[3];
    const s16x8 bv0 = ((const s16x8*)(rtrow + k0))[0];
    const s16x8 bv1 = ((const s16x8*)(rtrow + k0))[1];

    s16x8 p0, p1;
#pragma unroll
    for (int j = 0; j < 4; ++j) {
      p0[j] = f2bf(v0[j]);
      p0[4 + j] = f2bf(v1[j]);
      p1[j] = f2bf(v2[j]);
      p1[4 + j] = f2bf(v3[j]);
    }

    __syncthreads();  // previous iteration's LDS reads complete
    *(s16x8*)&sA[arow][aseg] = p0;
    *(s16x8*)&sA[arow][aseg + 8] = p1;
    *(s16x8*)&sB[arow][aseg] = bv0;
    *(s16x8*)&sB[arow][aseg + 8] = bv1;
    __syncthreads();  // tile visible

    // ---- MFMA: 2 k-subtiles x (2x2 16x16 fragments) ----
#pragma unroll
    for (int kk = 0; kk < 64; kk += 32) {
      const int kb = kk + fq * 8;
      const s16x8 a0 = *(const s16x8*)&sA[wm * 32 + fr][kb];
      const s16x8 a1 = *(const s16x8*)&sA[wm * 32 + 16 + fr][kb];
      const s16x8 b0 = *(const s16x8*)&sB[wn * 32 + fr][kb];
      const s16x8 b1 = *(const s16x8*)&sB[wn * 32 + 16 + fr][kb];
      acc[0][0] = __builtin_amdgcn_mfma_f32_16x16x32_bf16(a0, b0, acc[0][0], 0, 0, 0);
      acc[0][1] = __builtin_amdgcn_mfma_f32_16x16x32_bf16(a0, b1, acc[0][1], 0, 0, 0);
      acc[1][0] = __builtin_amdgcn_mfma_f32_16x16x32_bf16(a1, b0, acc[1][0], 0, 0, 0);
      acc[1][1] = __builtin_amdgcn_mfma_f32_16x16x32_bf16(a1, b1, acc[1][1], 0, 0, 0);
    }
  }

  // ---- epilogue: C/D layout col=lane&15, row=(lane>>4)*4+reg (m89-verified) ----
#pragma unroll
  for (int mi = 0; mi < 2; ++mi) {
#pragma unroll
    for (int ni = 0; ni < 2; ++ni) {
      float* op = out + (size_t)(m0 + wm * 32 + mi * 16 + fq * 4) * 1024 +
                  (n0 + wn * 32 + ni * 16 + fr);
#pragma unroll
      for (int r = 0; r < 4; ++r) op[(size_t)r * 1024] = acc[mi][ni][r];
    }
  }
}

extern "C" void kernel_launch(void* const* d_in, const int* in_sizes, int n_in,
                              void* d_out, int out_size, void* d_ws, size_t ws_size,
                              hipStream_t stream) {
  const int* ids = (const int*)d_in[0];     // [4,4096] int32
  const float* W = (const float*)d_in[1];   // [50257,1024] f32
  const float* R = (const float*)d_in[2];   // [1024,1024] f32
  float* out = (float*)d_out;               // [4,4096,1024] f32
  short* RT = (short*)d_ws;                 // 2 MB bf16 R^T

  convert_R_kernel<<<dim3(32, 32), dim3(32, 8), 0, stream>>>(R, RT);
  rot_embed_gemm<<<dim3(4096), dim3(256), 0, stream>>>(W, RT, ids, out);
}

// Round 2
// 92.320 us; speedup vs baseline: 1.0119x; 1.0119x over previous
//
#include <hip/hip_runtime.h>
#include <hip/hip_bf16.h>

// RotatedEmbedding: out[m,:] = W[ids[m],:] @ R  (M=16384, K=N=1024)
// Fused gather-GEMM, 128x128 tile, BK=64, 4 waves (2x2), 16x16x32 bf16 MFMA.
// A (gathered W rows, f32) reg-staged with convert + swizzled ds_write,
// prefetched one K-tile ahead (T14). B (RT bf16) via global_load_lds with
// pre-swizzled source (rule #21). LDS rows XOR-swizzled (T2).

typedef __attribute__((ext_vector_type(4))) float f32x4;
typedef __attribute__((ext_vector_type(8))) short s16x8;

#define DIM 1024
#define BM 128
#define BN 128
#define BK 64

__device__ __forceinline__ short f2bf(float f) {
  unsigned u = __float_as_uint(f);
  unsigned r = (u + 0x7FFFu + ((u >> 16) & 1u)) >> 16;  // RNE
  return (short)r;
}

__device__ __forceinline__ void gload_lds16(const void* g, void* l) {
  __builtin_amdgcn_global_load_lds((const __attribute__((address_space(1))) void*)g,
                                   (__attribute__((address_space(3))) void*)l, 16, 0, 0);
}

// R [K][N] f32 -> RT [N][K] bf16
__global__ __launch_bounds__(256) void convert_R_kernel(const float* __restrict__ R,
                                                        short* __restrict__ RT) {
  __shared__ float tile[32][33];
  const int bx = blockIdx.x, by = blockIdx.y;
  const int tx = threadIdx.x, ty = threadIdx.y;
#pragma unroll
  for (int i = 0; i < 4; ++i)
    tile[ty + i * 8][tx] = R[(size_t)(by * 32 + ty + i * 8) * DIM + bx * 32 + tx];
  __syncthreads();
#pragma unroll
  for (int i = 0; i < 4; ++i)
    RT[(size_t)(bx * 32 + ty + i * 8) * DIM + by * 32 + tx] = f2bf(tile[tx][ty + i * 8]);
}

__global__ __launch_bounds__(256) void rot_embed_gemm(const float* __restrict__ W,
                                                      const short* __restrict__ RT,
                                                      const int* __restrict__ ids,
                                                      float* __restrict__ out) {
  // linear LDS, XOR-swizzled addressing: byte = row*128 + ((chunk ^ (row&7))<<4)
  __shared__ short sA[BM * BK];  // 16 KB
  __shared__ short sB[BN * BK];  // 16 KB
  __shared__ int sIds[BM];

  const int t = threadIdx.x;
  const int b = blockIdx.x;
  // XCD-bijective swizzle (1024 % 8 == 0): XCD x owns m-tiles [x*16,(x+1)*16) all n
  const int swz = (b & 7) * 128 + (b >> 3);
  const int m0 = (swz >> 3) * BM;
  const int n0 = (swz & 7) * BN;

  if (t < BM) sIds[t] = ids[m0 + t];
  __syncthreads();

  const int lane = t & 63;
  const int w = t >> 6;
  const int wm = w & 1;   // wave row (0/1)
  const int wn = w >> 1;  // wave col (0/1)
  const int fr = lane & 15;
  const int fq = lane >> 4;

  // A staging: thread t -> row t>>1 (0..127), half t&1 (32 f32 = 8x f32x4)
  const int arow = t >> 1;
  const int ahalf = t & 1;
  const float* aptr = W + (size_t)sIds[arow] * DIM + ahalf * 32;

  // B staging (global_load_lds): wave w inst j covers LDS rows (w*4+j)*8..+8
  const int brow_in = lane >> 3;  // 0..7
  const int bchunk = lane & 7;    // 16B chunk in row

  f32x4 av[8];
#pragma unroll
  for (int j = 0; j < 8; ++j) av[j] = ((const f32x4*)aptr)[j];

  f32x4 acc[4][4];
#pragma unroll
  for (int i = 0; i < 4; ++i)
#pragma unroll
    for (int j = 0; j < 4; ++j) acc[i][j] = (f32x4)0.0f;

  for (int k0 = 0; k0 < DIM; k0 += BK) {
    // convert prefetched A (vmcnt wait lands here, hidden under prev MFMA)
    s16x8 p[4];
#pragma unroll
    for (int j = 0; j < 4; ++j)
#pragma unroll
      for (int e = 0; e < 4; ++e) {
        p[j][e] = f2bf(av[2 * j][e]);
        p[j][4 + e] = f2bf(av[2 * j + 1][e]);
      }

    __syncthreads();  // all waves finished reading previous tile

    // A: swizzled ds_write_b128 x4 (chunks ahalf*4+j)
#pragma unroll
    for (int j = 0; j < 4; ++j) {
      const int c = ahalf * 4 + j;
      *(s16x8*)((char*)sA + arow * 128 + ((c ^ (arow & 7)) << 4)) = p[j];
    }
    // B: global_load_lds, source pre-swizzled so LDS linear dest == swizzled layout
#pragma unroll
    for (int j = 0; j < 4; ++j) {
      const int r = (w * 4 + j) * 8 + brow_in;
      const short* src = RT + (size_t)(n0 + r) * DIM + k0 + ((bchunk ^ (r & 7)) << 3);
      gload_lds16(src, (char*)sB + (size_t)(w * 4 + j) * 1024);
    }

    __syncthreads();  // tile visible (vmcnt0+lgkmcnt0 drain: B + A-writes only)

    // T14: prefetch next A AFTER the drain barrier -> latency hides under MFMA
    if (k0 + BK < DIM) {
      const float* np = aptr + k0 + BK;
#pragma unroll
      for (int j = 0; j < 8; ++j) av[j] = ((const f32x4*)np)[j];
    }

    // MFMA: 2 k-subtiles x 4x4 fragments
#pragma unroll
    for (int kk = 0; kk < BK; kk += 32) {
      const int cbase = (kk >> 3) + fq;
      s16x8 af[4], bfr[4];
#pragma unroll
      for (int i = 0; i < 4; ++i) {
        const int ra = wm * 64 + i * 16 + fr;
        af[i] = *(const s16x8*)((const char*)sA + ra * 128 + ((cbase ^ (ra & 7)) << 4));
        const int rb = wn * 64 + i * 16 + fr;
        bfr[i] = *(const s16x8*)((const char*)sB + rb * 128 + ((cbase ^ (rb & 7)) << 4));
      }
#pragma unroll
      for (int i = 0; i < 4; ++i)
#pragma unroll
        for (int j = 0; j < 4; ++j)
          acc[i][j] = __builtin_amdgcn_mfma_f32_16x16x32_bf16(af[i], bfr[j], acc[i][j], 0, 0, 0);
    }
  }

  // epilogue: D col=lane&15, row=(lane>>4)*4+reg (m89-verified)
#pragma unroll
  for (int i = 0; i < 4; ++i)
#pragma unroll
    for (int j = 0; j < 4; ++j) {
      float* op = out + (size_t)(m0 + wm * 64 + i * 16 + fq * 4) * DIM +
                  (n0 + wn * 64 + j * 16 + fr);
#pragma unroll
      for (int r = 0; r < 4; ++r) op[(size_t)r * DIM] = acc[i][j][r];
    }
}

extern "C" void kernel_launch(void* const* d_in, const int* in_sizes, int n_in,
                              void* d_out, int out_size, void* d_ws, size_t ws_size,
                              hipStream_t stream) {
  const int* ids = (const int*)d_in[0];    // [4,4096] int32
  const float* W = (const float*)d_in[1];  // [50257,1024] f32
  const float* R = (const float*)d_in[2];  // [1024,1024] f32
  float* out = (float*)d_out;              // [4,4096,1024] f32
  short* RT = (short*)d_ws;                // 2 MB bf16 R^T

  convert_R_kernel<<<dim3(32, 32), dim3(32, 8), 0, stream>>>(R, RT);
  rot_embed_gemm<<<dim3(1024), dim3(256), 0, stream>>>(W, RT, ids, out);
}

// Round 3
// 79.387 us; speedup vs baseline: 1.1767x; 1.1629x over previous
//
#include <hip/hip_runtime.h>
#include <hip/hip_bf16.h>

// RotatedEmbedding: out[m,:] = W[ids[m],:] @ R  (M=16384, K=N=1024)
// Two-stage: (1) gather+convert W rows -> G bf16 (streaming, latency-immune)
//            (2) m97-structure bf16 GEMM: G[M,K] x RT[N,K] -> out, both
//                operands staged via global_load_lds width-16, 128x128 tile.

typedef __attribute__((ext_vector_type(4))) float f32x4;
typedef __attribute__((ext_vector_type(8))) short s16x8;
typedef __attribute__((ext_vector_type(2))) int i32x2;

#define DIM 1024
#define BM 128
#define BN 128
#define BK 64

__device__ __forceinline__ short f2bf(float f) {
  unsigned u = __float_as_uint(f);
  unsigned r = (u + 0x7FFFu + ((u >> 16) & 1u)) >> 16;  // RNE
  return (short)r;
}

__device__ __forceinline__ void gload_lds16(const void* g, void* l) {
  __builtin_amdgcn_global_load_lds((const __attribute__((address_space(1))) void*)g,
                                   (__attribute__((address_space(3))) void*)l, 16, 0, 0);
}

// R [K][N] f32 -> RT [N][K] bf16
__global__ __launch_bounds__(256) void convert_R_kernel(const float* __restrict__ R,
                                                        short* __restrict__ RT) {
  __shared__ float tile[32][33];
  const int bx = blockIdx.x, by = blockIdx.y;
  const int tx = threadIdx.x, ty = threadIdx.y;
#pragma unroll
  for (int i = 0; i < 4; ++i)
    tile[ty + i * 8][tx] = R[(size_t)(by * 32 + ty + i * 8) * DIM + bx * 32 + tx];
  __syncthreads();
#pragma unroll
  for (int i = 0; i < 4; ++i)
    RT[(size_t)(bx * 32 + ty + i * 8) * DIM + by * 32 + tx] = f2bf(tile[tx][ty + i * 8]);
}

// G[m][k] = bf16(W[ids[m]][k]); processed as f32x4 chunks, fully coalesced.
// 16384 rows x 256 chunks = 4,194,304 chunks; 2048 blk x 256 thr x 8 iters.
__global__ __launch_bounds__(256) void gather_convert(const float* __restrict__ W,
                                                      const int* __restrict__ ids,
                                                      short* __restrict__ G) {
  const int tid = blockIdx.x * 256 + threadIdx.x;
#pragma unroll
  for (int i = 0; i < 8; ++i) {
    const int g = tid + i * (2048 * 256);
    const int row = g >> 8;          // output row
    const int c4 = (g & 255) << 2;   // f32 col base (4 per chunk)
    const f32x4 v = *(const f32x4*)(W + (size_t)ids[row] * DIM + c4);
    i32x2 p;
    p[0] = (int)(unsigned short)f2bf(v[0]) | ((int)f2bf(v[1]) << 16);
    p[1] = (int)(unsigned short)f2bf(v[2]) | ((int)f2bf(v[3]) << 16);
    *(i32x2*)(G + (size_t)g * 4) = p;
  }
}

// m97-structure GEMM: out[M,N] = G[M,K] * RT[N,K]^T
__global__ __launch_bounds__(256) void rot_embed_gemm(const short* __restrict__ G,
                                                      const short* __restrict__ RT,
                                                      float* __restrict__ out) {
  __shared__ short sA[BM * BK];  // 16 KB, linear [row][64]
  __shared__ short sB[BN * BK];  // 16 KB

  const int t = threadIdx.x;
  const int b = blockIdx.x;
  // XCD-bijective swizzle (1024 blocks): XCD x -> m-tiles [x*16,(x+1)*16), all n
  const int swz = (b & 7) * 128 + (b >> 3);
  const int m0 = (swz >> 3) * BM;
  const int n0 = (swz & 7) * BN;

  const int lane = t & 63;
  const int w = t >> 6;
  const int wm = w & 1;
  const int wn = w >> 1;
  const int fr = lane & 15;
  const int fq = lane >> 4;

  // staging: wave w, instr j covers LDS bytes [(w*4+j)*1024, +1024)
  // lane l -> row (w*4+j)*8 + (l>>3), col elems (l&7)*8
  const int srow = (lane >> 3);
  const int scol = (lane & 7) * 8;

  f32x4 acc[4][4];
#pragma unroll
  for (int i = 0; i < 4; ++i)
#pragma unroll
    for (int j = 0; j < 4; ++j) acc[i][j] = (f32x4)0.0f;

  for (int k0 = 0; k0 < DIM; k0 += BK) {
    __syncthreads();  // previous tile's reads complete
#pragma unroll
    for (int j = 0; j < 4; ++j) {
      const int r = (w * 4 + j) * 8 + srow;
      gload_lds16(G + (size_t)(m0 + r) * DIM + k0 + scol,
                  (char*)sA + (size_t)(w * 4 + j) * 1024);
      gload_lds16(RT + (size_t)(n0 + r) * DIM + k0 + scol,
                  (char*)sB + (size_t)(w * 4 + j) * 1024);
    }
    __syncthreads();  // drain (vmcnt0) -> tile visible

#pragma unroll
    for (int kk = 0; kk < BK; kk += 32) {
      s16x8 af[4], bfr[4];
#pragma unroll
      for (int i = 0; i < 4; ++i) {
        af[i] = *(const s16x8*)&sA[(wm * 64 + i * 16 + fr) * BK + kk + fq * 8];
        bfr[i] = *(const s16x8*)&sB[(wn * 64 + i * 16 + fr) * BK + kk + fq * 8];
      }
#pragma unroll
      for (int i = 0; i < 4; ++i)
#pragma unroll
        for (int j = 0; j < 4; ++j)
          acc[i][j] = __builtin_amdgcn_mfma_f32_16x16x32_bf16(af[i], bfr[j], acc[i][j], 0, 0, 0);
    }
  }

  // epilogue: D col=lane&15, row=(lane>>4)*4+reg (m89-verified)
#pragma unroll
  for (int i = 0; i < 4; ++i)
#pragma unroll
    for (int j = 0; j < 4; ++j) {
      float* op = out + (size_t)(m0 + wm * 64 + i * 16 + fq * 4) * DIM +
                  (n0 + wn * 64 + j * 16 + fr);
#pragma unroll
      for (int r = 0; r < 4; ++r) op[(size_t)r * DIM] = acc[i][j][r];
    }
}

extern "C" void kernel_launch(void* const* d_in, const int* in_sizes, int n_in,
                              void* d_out, int out_size, void* d_ws, size_t ws_size,
                              hipStream_t stream) {
  const int* ids = (const int*)d_in[0];    // [4,4096] int32
  const float* W = (const float*)d_in[1];  // [50257,1024] f32
  const float* R = (const float*)d_in[2];  // [1024,1024] f32
  float* out = (float*)d_out;              // [4,4096,1024] f32
  short* RT = (short*)d_ws;                // 2 MB bf16 R^T
  short* G = (short*)d_ws + (size_t)DIM * DIM;  // 32 MB bf16 gathered rows

  convert_R_kernel<<<dim3(32, 32), dim3(32, 8), 0, stream>>>(R, RT);
  gather_convert<<<dim3(2048), dim3(256), 0, stream>>>(W, ids, G);
  rot_embed_gemm<<<dim3(1024), dim3(256), 0, stream>>>(G, RT, out);
}

// Round 4
// 60.848 us; speedup vs baseline: 1.5353x; 1.3047x over previous
//
#include <hip/hip_runtime.h>
#include <hip/hip_bf16.h>

// RotatedEmbedding: out[m,:] = W[ids[m],:] @ R  (M=16384, K=N=1024)
// Stage 1 (prep): convert R->RT bf16 (transposed)  ||  gather W rows -> G bf16.
// Stage 2: 256x256-tile GEMM, BK=32, 8 waves, 3 LDS buffers, 2-tile counted-
//          vmcnt prefetch (T3/T4), chunk-XOR LDS swizzle (T2), setprio (T5),
//          XCD-bijective block swizzle (T1). One s_barrier per K-tile.

typedef __attribute__((ext_vector_type(4))) float f32x4;
typedef __attribute__((ext_vector_type(8))) short s16x8;
typedef __attribute__((ext_vector_type(2))) int i32x2;

#define DIM 1024
#define BKT 32   // K per tile
#define NT 32    // 1024 / 32 K-tiles
#define BUF_SH (256 * BKT)  // shorts per operand buffer (16 KB)

__device__ __forceinline__ short f2bf(float f) {
  unsigned u = __float_as_uint(f);
  unsigned r = (u + 0x7FFFu + ((u >> 16) & 1u)) >> 16;  // RNE
  return (short)r;
}

__device__ __forceinline__ void gload_lds16(const void* g, void* l) {
  __builtin_amdgcn_global_load_lds((const __attribute__((address_space(1))) void*)g,
                                   (__attribute__((address_space(3))) void*)l, 16, 0, 0);
}

// Fused: blocks [0,1024) transpose+convert R -> RT; blocks [1024,3072) gather
// W rows by ids -> G bf16. Independent work, one launch (overlapped).
__global__ __launch_bounds__(256) void prep_kernel(const float* __restrict__ R,
                                                   short* __restrict__ RT,
                                                   const float* __restrict__ W,
                                                   const int* __restrict__ ids,
                                                   short* __restrict__ G) {
  const int b = blockIdx.x;
  const int t = threadIdx.x;
  if (b < 1024) {  // R [K][N] f32 -> RT [N][K] bf16
    __shared__ float tile[32][33];
    const int bx = b & 31, by = b >> 5;
    const int tx = t & 31, ty = t >> 5;
#pragma unroll
    for (int i = 0; i < 4; ++i)
      tile[ty + i * 8][tx] = R[(size_t)(by * 32 + ty + i * 8) * DIM + bx * 32 + tx];
    __syncthreads();
#pragma unroll
    for (int i = 0; i < 4; ++i)
      RT[(size_t)(bx * 32 + ty + i * 8) * DIM + by * 32 + tx] = f2bf(tile[tx][ty + i * 8]);
  } else {  // gather: G[m][k] = bf16(W[ids[m]][k]); 1 row per block-iter, coalesced
    const int tid = (b - 1024) * 256 + t;
#pragma unroll
    for (int i = 0; i < 8; ++i) {
      const int g = tid + i * (2048 * 256);
      const int row = g >> 8;
      const int c4 = (g & 255) << 2;
      const f32x4 v = *(const f32x4*)(W + (size_t)ids[row] * DIM + c4);
      i32x2 p;
      p[0] = (int)(unsigned short)f2bf(v[0]) | ((int)f2bf(v[1]) << 16);
      p[1] = (int)(unsigned short)f2bf(v[2]) | ((int)f2bf(v[3]) << 16);
      *(i32x2*)(G + (size_t)g * 4) = p;
    }
  }
}

// GEMM: out[M,N] = G[M,K] * RT[N,K]^T.  Grid 256 blocks x 512 threads.
// LDS (dynamic 96 KB): sA[3][256][32], sB[3][256][32] bf16, rows of 64 B.
// Swizzle: LDS (row, chunk c) holds logical chunk c ^ (row & 3)  (16B chunks).
__global__ __launch_bounds__(512, 2) void rot_embed_gemm(const short* __restrict__ G,
                                                         const short* __restrict__ RT,
                                                         float* __restrict__ out) {
  extern __shared__ char smem[];  // [0,48K): sA bufs, [48K,96K): sB bufs

  const int t = threadIdx.x;
  const int b = blockIdx.x;
  // T1: XCD-bijective swizzle (256 % 8 == 0): XCD x -> m-panels [x*8,(x+1)*8), all n
  const int swz = (b & 7) * 32 + (b >> 3);
  const int m0 = (swz >> 2) * 256;  // 64 m-tiles
  const int n0 = (swz & 3) * 256;   // 4 n-tiles

  const int lane = t & 63;
  const int w = t >> 6;   // wave 0..7
  const int wm = w >> 2;  // 0..1: output rows wm*128..+128
  const int wn = w & 3;   // 0..3: output cols wn*64..+64
  const int fr = lane & 15;
  const int fq = lane >> 4;

  // Staging: instr j in {0,1} per operand; wave w covers rows j*128 + w*16 + (lane>>2),
  // source chunk pre-swizzled: (lane&3) ^ ((lane>>2)&3)  [rule #21: linear LDS dest]
  const int srow = w * 16 + (lane >> 2);
  const int schunk = ((lane & 3) ^ ((lane >> 2) & 3)) * 8;  // bf16 elems
  const short* gA0 = G + (size_t)(m0 + srow) * DIM + schunk;
  const short* gA1 = G + (size_t)(m0 + 128 + srow) * DIM + schunk;
  const short* gB0 = RT + (size_t)(n0 + srow) * DIM + schunk;
  const short* gB1 = RT + (size_t)(n0 + 128 + srow) * DIM + schunk;

  char* const ldsA = smem;
  char* const ldsB = smem + 3 * 32768 / 2;  // 49152

#define STAGE(kt, d)                                             \
  {                                                              \
    const int ko = (kt) * BKT;                                   \
    char* la = ldsA + (d) * 16384 + w * 1024;                    \
    char* lb = ldsB + (d) * 16384 + w * 1024;                    \
    gload_lds16(gA0 + ko, la);                                   \
    gload_lds16(gA1 + ko, la + 8192);                            \
    gload_lds16(gB0 + ko, lb);                                   \
    gload_lds16(gB1 + ko, lb + 8192);                            \
  }

  f32x4 acc[8][4];
#pragma unroll
  for (int i = 0; i < 8; ++i)
#pragma unroll
    for (int j = 0; j < 4; ++j) acc[i][j] = (f32x4)0.0f;

  // Prologue: 2 tiles in flight (8 vmem instrs/wave outstanding)
  STAGE(0, 0);
  STAGE(1, 1);

  for (int kt = 0; kt < NT; ++kt) {
    // T4: counted vmcnt — wait tile kt landed (tile kt+1's 4 instrs stay in flight)
    if (kt == NT - 1)
      asm volatile("s_waitcnt vmcnt(0)" ::: "memory");
    else
      asm volatile("s_waitcnt vmcnt(4)" ::: "memory");
    __builtin_amdgcn_s_barrier();          // all waves: tile kt visible; prev reads done
    __builtin_amdgcn_sched_barrier(0);

    // prefetch tile kt+2 into buf (kt+2)%3 — touched by no reader this iter or next
    if (kt + 2 < NT) STAGE(kt + 2, (kt + 2) % 3);

    const char* A = ldsA + (kt % 3) * 16384;
    const char* B = ldsB + (kt % 3) * 16384;

    // swizzled ds_read: byte = row*64 + ((fq ^ (fr&3))<<4) -> logical chunk fq
    const int sc = (fq ^ (fr & 3)) << 4;
    s16x8 af[8], bf[4];
#pragma unroll
    for (int mi = 0; mi < 8; ++mi)
      af[mi] = *(const s16x8*)(A + (wm * 128 + mi * 16 + fr) * 64 + sc);
#pragma unroll
    for (int nj = 0; nj < 4; ++nj)
      bf[nj] = *(const s16x8*)(B + (wn * 64 + nj * 16 + fr) * 64 + sc);

    __builtin_amdgcn_s_setprio(1);  // T5
#pragma unroll
    for (int mi = 0; mi < 8; ++mi)
#pragma unroll
      for (int nj = 0; nj < 4; ++nj)
        acc[mi][nj] = __builtin_amdgcn_mfma_f32_16x16x32_bf16(af[mi], bf[nj], acc[mi][nj], 0, 0, 0);
    __builtin_amdgcn_s_setprio(0);
  }

  // epilogue: D col=lane&15, row=(lane>>4)*4+reg (m89-verified)
#pragma unroll
  for (int mi = 0; mi < 8; ++mi)
#pragma unroll
    for (int nj = 0; nj < 4; ++nj) {
      float* op = out + (size_t)(m0 + wm * 128 + mi * 16 + fq * 4) * DIM +
                  (n0 + wn * 64 + nj * 16 + fr);
#pragma unroll
      for (int r = 0; r < 4; ++r) op[(size_t)r * DIM] = acc[mi][nj][r];
    }
#undef STAGE
}

extern "C" void kernel_launch(void* const* d_in, const int* in_sizes, int n_in,
                              void* d_out, int out_size, void* d_ws, size_t ws_size,
                              hipStream_t stream) {
  const int* ids = (const int*)d_in[0];    // [4,4096] int32
  const float* W = (const float*)d_in[1];  // [50257,1024] f32
  const float* R = (const float*)d_in[2];  // [1024,1024] f32
  float* out = (float*)d_out;              // [4,4096,1024] f32
  short* RT = (short*)d_ws;                // 2 MB bf16 R^T
  short* G = (short*)d_ws + (size_t)DIM * DIM;  // 32 MB bf16 gathered rows

  prep_kernel<<<dim3(3072), dim3(256), 0, stream>>>(R, RT, W, ids, G);
  rot_embed_gemm<<<dim3(256), dim3(512), 98304, stream>>>(G, RT, out);
}